// Round 1
// baseline (31.826 us; speedup 1.0000x reference)
//
#include <hip/hip_runtime.h>
#include <hip/hip_bf16.h>

// out[b,i,j] = dot(head[b,i,:], W[:D]) + dot(dep[b,j,:], W[D:]) + b0
// B=16, S=1024, D=768.  Memory-bound: 96 MiB in + 64 MiB out.

#define B_SZ 16
#define S_SZ 1024
#define D_SZ 768   // 192 float4 per row; 3 float4 per lane of a 64-wave

// Kernel 1: one wave per row. Rows 0..BS-1 -> s_h (from head, w_h),
// rows BS..2BS-1 -> s_d (from dep, w_d). Results to ws[0..2BS).
__global__ __launch_bounds__(256) void dot_rows_kernel(
    const float* __restrict__ head,
    const float* __restrict__ dep,
    const float* __restrict__ edge_W,
    float* __restrict__ s_out)
{
    const int rows = B_SZ * S_SZ;                      // 16384
    const int wave = (blockIdx.x * blockDim.x + threadIdx.x) >> 6;
    const int lane = threadIdx.x & 63;
    if (wave >= 2 * rows) return;

    const float* src;
    const float* w;
    int row;
    if (wave < rows) { src = head; w = edge_W;         row = wave; }
    else             { src = dep;  w = edge_W + D_SZ;  row = wave - rows; }

    const float4* __restrict__ p  =
        reinterpret_cast<const float4*>(src + (size_t)row * D_SZ);
    const float4* __restrict__ wp = reinterpret_cast<const float4*>(w);

    float acc = 0.f;
#pragma unroll
    for (int k = 0; k < 3; ++k) {
        float4 a = p[lane + k * 64];
        float4 b = wp[lane + k * 64];
        acc += a.x * b.x + a.y * b.y + a.z * b.z + a.w * b.w;
    }
    // wave-64 butterfly reduce
#pragma unroll
    for (int off = 32; off > 0; off >>= 1)
        acc += __shfl_down(acc, off, 64);

    if (lane == 0) s_out[wave] = acc;
}

// Kernel 2: one block per output row (b,i); 256 threads x float4 = 1024 j's.
__global__ __launch_bounds__(256) void bcast_kernel(
    const float* __restrict__ s_h,
    const float* __restrict__ s_d,
    const float* __restrict__ edge_b,
    float* __restrict__ out)
{
    const int row = blockIdx.x;            // b*S + i, 0..16383
    const int b   = row >> 10;             // S = 1024
    const int t   = threadIdx.x;           // 0..255

    const float base = s_h[row] + edge_b[0];
    float4 sd = reinterpret_cast<const float4*>(s_d + ((size_t)b << 10))[t];

    float4 o;
    o.x = base + sd.x;
    o.y = base + sd.y;
    o.z = base + sd.z;
    o.w = base + sd.w;
    reinterpret_cast<float4*>(out + ((size_t)row << 10))[t] = o;
}

extern "C" void kernel_launch(void* const* d_in, const int* in_sizes, int n_in,
                              void* d_out, int out_size, void* d_ws, size_t ws_size,
                              hipStream_t stream) {
    const float* head   = (const float*)d_in[0];
    const float* dep    = (const float*)d_in[1];
    const float* edge_W = (const float*)d_in[2];
    const float* edge_b = (const float*)d_in[3];
    float* out = (float*)d_out;

    float* s = (float*)d_ws;               // [2 * B*S] floats = 128 KiB
    const int rows = B_SZ * S_SZ;          // 16384

    // Kernel 1: 2*rows waves, 4 waves per 256-thread block
    {
        int total_waves = 2 * rows;                    // 32768
        int blocks = (total_waves * 64 + 255) / 256;   // 8192
        dot_rows_kernel<<<blocks, 256, 0, stream>>>(head, dep, edge_W, s);
    }

    // Kernel 2: one block per (b,i) row
    {
        bcast_kernel<<<rows, 256, 0, stream>>>(s, s + rows, edge_b, out);
    }
}